// Round 3
// baseline (236.982 us; speedup 1.0000x reference)
//
#include <hip/hip_runtime.h>
#include <hip/hip_bf16.h>

// MambaSP R3: one kernel per layer (4 dispatches). Chunked scan with
// publish->lookback (aggregates-only, deadlock-free: publish precedes any
// wait). NC=32 chunks x CL=128. Per-layer PS + flag arrays so stale flags
// across graph replays still read identical data.

constexpr int   Bsz = 32;
constexpr int   Lsz = 4096;
constexpr int   NC  = 32;
constexpr int   CL  = 128;
constexpr int   T   = 32;          // reduction tile (steps)
constexpr float SRinv = 1.0f / 4096.0f;

__device__ __forceinline__ float sigmoidf_(float v) {
    return 1.0f / (1.0f + __expf(-v));
}

__global__ __launch_bounds__(128, 2) void k_layer(
    const float* __restrict__ xin,    // [B,L] layer input
    const float* __restrict__ W_in,   // [4]
    const float* __restrict__ conv_w, // [2,4]
    const float* __restrict__ conv_b, // [2]
    const float* __restrict__ W_x,    // [2,129]
    const float* __restrict__ W_dt,   // [2]
    const float* __restrict__ b_dt,   // [2]
    const float* __restrict__ A_log,  // [2,64]
    const float* __restrict__ D_skip, // [2]
    const float* __restrict__ W_out,  // [2]
    float2* __restrict__ PS,          // [B,NC,128] this layer's aggregates
    unsigned int* __restrict__ flags, // [B,NC]     this layer's flags (poisoned 0xAA..)
    float* __restrict__ out)          // [B,L]
{
    const int c = blockIdx.x, b = blockIdx.y, tid = threadIdx.x;
    __shared__ float  xs[CL + 3];     // x with left halo of 3
    __shared__ float4 s_ud[CL];       // {u0,u1,d0,d1}
    __shared__ float  ps[2 * T * 65]; // rows (t*2+e), stride 65
    __shared__ float  pp[128];
    const int base = b * Lsz + c * CL;

    for (int i = tid; i < CL + 3; i += 128) {
        int l = c * CL + i - 3;
        xs[i] = (l >= 0) ? xin[b * Lsz + l] : 0.0f;
    }
    __syncthreads();

    // preprocess: thread t = position t of the chunk
    {
        const int t = tid;
        float x0 = xs[t], x1 = xs[t + 1], x2 = xs[t + 2], x3 = xs[t + 3];
        float u0, u1;
        {
            float v = W_in[0] * (x0 * conv_w[0] + x1 * conv_w[1] + x2 * conv_w[2] + x3 * conv_w[3]) + conv_b[0];
            u0 = v * sigmoidf_(v);
        }
        {
            float v = W_in[1] * (x0 * conv_w[4] + x1 * conv_w[5] + x2 * conv_w[6] + x3 * conv_w[7]) + conv_b[1];
            u1 = v * sigmoidf_(v);
        }
        float dt = u0 * W_x[0] + u1 * W_x[129];
        float a0 = dt * W_dt[0] + b_dt[0];
        float a1 = dt * W_dt[1] + b_dt[1];
        float d0 = ((a0 > 20.0f) ? a0 : log1pf(__expf(a0))) * SRinv;
        float d1 = ((a1 > 20.0f) ? a1 : log1pf(__expf(a1))) * SRinv;
        s_ud[t] = make_float4(u0, u1, d0, d1);
    }
    __syncthreads();

    const int e = tid >> 6, n = tid & 63;       // e uniform per wave
    const float Aen = -__expf(A_log[e * 64 + n]);
    const float wb0 = W_x[1 + n],  wb1 = W_x[129 + 1 + n];
    const float wc0 = W_x[65 + n], wc1 = W_x[129 + 65 + n];
    const float wz0 = W_in[2], wz1 = W_in[3];
    const float D0 = D_skip[0], D1 = D_skip[1];
    const float wo0 = W_out[0], wo1 = W_out[1];

    // ---- phase 1: local aggregate (P,S); publish (never waits first) ----
    if (c < NC - 1) {
        float P = 1.0f, S = 0.0f;
        if (e == 0) {
            #pragma unroll 8
            for (int l = 0; l < CL; l++) {
                float4 v = s_ud[l];
                float Bn = v.x * wb0 + v.y * wb1;
                float dA = __expf(v.z * Aen);
                S = dA * S + (v.z * v.x) * Bn;
                P *= dA;
            }
        } else {
            #pragma unroll 8
            for (int l = 0; l < CL; l++) {
                float4 v = s_ud[l];
                float Bn = v.x * wb0 + v.y * wb1;
                float dA = __expf(v.w * Aen);
                S = dA * S + (v.w * v.y) * Bn;
                P *= dA;
            }
        }
        float2 psv = make_float2(P, S);
        unsigned long long q = __builtin_bit_cast(unsigned long long, psv);
        __hip_atomic_store((unsigned long long*)&PS[(b * NC + c) * 128 + tid], q,
                           __ATOMIC_RELAXED, __HIP_MEMORY_SCOPE_AGENT);
        __syncthreads();   // all 128 stores issued+drained before flag
        if (tid == 0)
            __hip_atomic_store(&flags[b * NC + c], 1u,
                               __ATOMIC_RELEASE, __HIP_MEMORY_SCOPE_AGENT);
    }

    // ---- lookback: wait for all predecessor aggregates, compose pipelined ----
    float h = 0.0f;
    if (c > 0) {
        if (tid < 64) {
            bool need = tid < c;
            while (true) {
                unsigned int f = need
                    ? __hip_atomic_load(&flags[b * NC + tid], __ATOMIC_ACQUIRE, __HIP_MEMORY_SCOPE_AGENT)
                    : 1u;
                if (__ballot(f != 1u) == 0ull) break;
                __builtin_amdgcn_s_sleep(1);
            }
        }
        __syncthreads();
        const unsigned long long* psq =
            (const unsigned long long*)(PS + (size_t)(b * NC) * 128 + tid);
        int cp = 0;
        for (; cp + 8 <= c; cp += 8) {
            unsigned long long q[8];
            #pragma unroll
            for (int j = 0; j < 8; j++)
                q[j] = __hip_atomic_load(psq + (size_t)(cp + j) * 128,
                                         __ATOMIC_RELAXED, __HIP_MEMORY_SCOPE_AGENT);
            #pragma unroll
            for (int j = 0; j < 8; j++) {
                float2 v = __builtin_bit_cast(float2, q[j]);
                h = v.x * h + v.y;
            }
        }
        for (; cp < c; cp++) {
            unsigned long long q = __hip_atomic_load(psq + (size_t)cp * 128,
                                                     __ATOMIC_RELAXED, __HIP_MEMORY_SCOPE_AGENT);
            float2 v = __builtin_bit_cast(float2, q);
            h = v.x * h + v.y;
        }
    }

    // ---- phase 2: rescan with h, LDS reduce over n, epilogue ----
    for (int tile = 0; tile < CL / T; tile++) {
        const int t0 = tile * T;
        if (e == 0) {
            #pragma unroll 8
            for (int t = 0; t < T; t++) {
                float4 v = s_ud[t0 + t];
                float Bn = v.x * wb0 + v.y * wb1;
                float Cn = v.x * wc0 + v.y * wc1;
                float dA = __expf(v.z * Aen);
                h = dA * h + (v.z * v.x) * Bn;
                ps[(t * 2 + 0) * 65 + n] = h * Cn;
            }
        } else {
            #pragma unroll 8
            for (int t = 0; t < T; t++) {
                float4 v = s_ud[t0 + t];
                float Bn = v.x * wb0 + v.y * wb1;
                float Cn = v.x * wc0 + v.y * wc1;
                float dA = __expf(v.w * Aen);
                h = dA * h + (v.w * v.y) * Bn;
                ps[(t * 2 + 1) * 65 + n] = h * Cn;
            }
        }
        __syncthreads();
        {
            const int r = tid >> 1, half = tid & 1;
            const float* row = &ps[r * 65 + half * 32];
            float a0 = 0, a1 = 0, a2 = 0, a3 = 0;
            #pragma unroll
            for (int j = 0; j < 32; j += 4) {
                a0 += row[j]; a1 += row[j + 1]; a2 += row[j + 2]; a3 += row[j + 3];
            }
            pp[tid] = (a0 + a1) + (a2 + a3);
        }
        __syncthreads();
        if (tid < T) {
            int l = t0 + tid;
            float4 v = s_ud[l];
            float y0 = pp[(l - t0) * 0 + (tid * 2 + 0) * 2 + 0] + pp[(tid * 2 + 0) * 2 + 1] + v.x * D0;
            float y1 = pp[(tid * 2 + 1) * 2 + 0] + pp[(tid * 2 + 1) * 2 + 1] + v.y * D1;
            float xv = xs[l + 3];
            float z0 = xv * wz0, z1 = xv * wz1;
            out[base + l] = y0 * (z0 * sigmoidf_(z0)) * wo0 +
                            y1 * (z1 * sigmoidf_(z1)) * wo1 + xv;
        }
        __syncthreads();
    }
}

extern "C" void kernel_launch(void* const* d_in, const int* in_sizes, int n_in,
                              void* d_out, int out_size, void* d_ws, size_t ws_size,
                              hipStream_t stream) {
    const float* x      = (const float*)d_in[0];
    const float* W_in   = (const float*)d_in[1];   // [4,1,4]
    const float* conv_w = (const float*)d_in[2];   // [4,2,4]
    const float* conv_b = (const float*)d_in[3];   // [4,2]
    const float* W_x    = (const float*)d_in[4];   // [4,2,129]
    const float* W_dt   = (const float*)d_in[5];   // [4,1,2]
    const float* b_dt   = (const float*)d_in[6];   // [4,2]
    const float* A_log  = (const float*)d_in[7];   // [4,2,64]
    const float* D_skip = (const float*)d_in[8];   // [4,2]
    const float* W_out  = (const float*)d_in[9];   // [4,2,1]
    float* out = (float*)d_out;

    float* ws = (float*)d_ws;
    // per-layer PS buffers: 4 * B*NC*128 float2
    float2* PSb = (float2*)ws;
    size_t ps_elems = (size_t)4 * Bsz * NC * 128;          // float2 count
    unsigned int* flagsB = (unsigned int*)(ws + ps_elems * 2);
    size_t flag_words = (size_t)4 * Bsz * NC;
    float* buf0 = ws + ps_elems * 2 + flag_words;
    float* buf1 = buf0 + (size_t)Bsz * Lsz;

    const float* cur = x;
    for (int i = 0; i < 4; i++) {
        float* o = (i == 3) ? out : ((i & 1) ? buf1 : buf0);
        k_layer<<<dim3(NC, Bsz), 128, 0, stream>>>(
            cur, W_in + i * 4, conv_w + i * 8, conv_b + i * 2,
            W_x + i * 258, W_dt + i * 2, b_dt + i * 2, A_log + i * 128,
            D_skip + i * 2, W_out + i * 2,
            PSb + (size_t)i * Bsz * NC * 128,
            flagsB + (size_t)i * Bsz * NC,
            o);
        cur = o;
    }
}

// Round 4
// 169.450 us; speedup vs baseline: 1.3985x; 1.3985x over previous
//
#include <hip/hip_runtime.h>
#include <hip/hip_bf16.h>

// MambaSP R4: 2 dispatches/layer (8 total), no cross-block sync primitives.
// kA: preprocess (conv+silu+softplus) -> ud[] + per-chunk aggregates PS.
// kB: batched-load prefix compose (pipelined, not a dependent-load chain),
//     rescan + LDS n-reduction + fused epilogue.
// NC=32 chunks x CL=128. All intermediates (~3MB) are L2/L3-resident.

constexpr int   Bsz = 32;
constexpr int   Lsz = 4096;
constexpr int   NC  = 32;
constexpr int   CL  = 128;
constexpr int   T   = 32;            // reduction tile (time steps)
constexpr int   PSTR = 66;           // ps row stride (even -> 8B aligned, 2-way banks)
constexpr float SRinv = 1.0f / 4096.0f;

__device__ __forceinline__ float sigmoidf_(float v) {
    return 1.0f / (1.0f + __expf(-v));
}

// ---------------- kA: preprocess + per-chunk (P,S) ----------------
__global__ __launch_bounds__(128) void k_scanA(
    const float* __restrict__ xin,    // [B,L]
    const float* __restrict__ W_in,   // [4]
    const float* __restrict__ conv_w, // [2,4]
    const float* __restrict__ conv_b, // [2]
    const float* __restrict__ W_x,    // [2,129]
    const float* __restrict__ W_dt,   // [2]
    const float* __restrict__ b_dt,   // [2]
    const float* __restrict__ A_log,  // [2,64]
    float4* __restrict__ ud,          // [B*L] {u0,u1,d0,d1}
    float2* __restrict__ PS)          // [B,NC,128] {P,S}
{
    const int c = blockIdx.x, b = blockIdx.y, tid = threadIdx.x;
    __shared__ float  xs[CL + 3];
    __shared__ float4 s_ud[CL];
    const int base = b * Lsz + c * CL;

    for (int i = tid; i < CL + 3; i += 128) {
        int l = c * CL + i - 3;
        xs[i] = (l >= 0) ? xin[b * Lsz + l] : 0.0f;
    }
    __syncthreads();

    {
        const int t = tid;
        float x0 = xs[t], x1 = xs[t + 1], x2 = xs[t + 2], x3 = xs[t + 3];
        float v0 = W_in[0] * (x0 * conv_w[0] + x1 * conv_w[1] + x2 * conv_w[2] + x3 * conv_w[3]) + conv_b[0];
        float v1 = W_in[1] * (x0 * conv_w[4] + x1 * conv_w[5] + x2 * conv_w[6] + x3 * conv_w[7]) + conv_b[1];
        float u0 = v0 * sigmoidf_(v0);
        float u1 = v1 * sigmoidf_(v1);
        float dt = u0 * W_x[0] + u1 * W_x[129];
        float a0 = dt * W_dt[0] + b_dt[0];
        float a1 = dt * W_dt[1] + b_dt[1];
        float d0 = ((a0 > 20.0f) ? a0 : log1pf(__expf(a0))) * SRinv;
        float d1 = ((a1 > 20.0f) ? a1 : log1pf(__expf(a1))) * SRinv;
        float4 v4 = make_float4(u0, u1, d0, d1);
        s_ud[t] = v4;
        ud[base + t] = v4;
    }
    __syncthreads();

    if (c == NC - 1) return;          // last chunk's aggregate never consumed

    const int e = tid >> 6, n = tid & 63;   // e wave-uniform
    const float Aen = -__expf(A_log[e * 64 + n]);
    const float wb0 = W_x[1 + n], wb1 = W_x[129 + 1 + n];
    float P = 1.0f, S = 0.0f;
    if (e == 0) {
        #pragma unroll 8
        for (int l = 0; l < CL; l++) {
            float4 v = s_ud[l];
            float Bn = v.x * wb0 + v.y * wb1;
            float dA = __expf(v.z * Aen);
            S = dA * S + (v.z * v.x) * Bn;
            P *= dA;
        }
    } else {
        #pragma unroll 8
        for (int l = 0; l < CL; l++) {
            float4 v = s_ud[l];
            float Bn = v.x * wb0 + v.y * wb1;
            float dA = __expf(v.w * Aen);
            S = dA * S + (v.w * v.y) * Bn;
            P *= dA;
        }
    }
    PS[(b * NC + c) * 128 + tid] = make_float2(P, S);
}

// ---------------- kB: batched compose + rescan + reduce + epilogue ----------------
__global__ __launch_bounds__(128) void k_scanB(
    const float* __restrict__ xin,
    const float4* __restrict__ ud,
    const float2* __restrict__ PS,
    const float* __restrict__ W_in,   // z weights at [2],[3]
    const float* __restrict__ W_x,
    const float* __restrict__ A_log,
    const float* __restrict__ D_skip, // [2]
    const float* __restrict__ W_out,  // [2]
    float* __restrict__ out)          // [B,L]
{
    const int c = blockIdx.x, b = blockIdx.y, tid = threadIdx.x;
    __shared__ float4 s_ud[CL];
    __shared__ float  xs[CL];
    __shared__ float  ps[2 * T * PSTR];   // row (t*2+e), stride PSTR
    __shared__ float  pp[128];
    __shared__ float  s_out[CL];
    const int base = b * Lsz + c * CL;

    s_ud[tid] = ud[base + tid];
    xs[tid]   = xin[base + tid];

    // prefix compose: batched independent loads (pipelined), then fma chain
    float h = 0.0f;
    {
        const float2* p = PS + (size_t)(b * NC) * 128 + tid;
        int cp = 0;
        while (cp + 8 <= c) {
            float2 q[8];
            #pragma unroll
            for (int j = 0; j < 8; j++) q[j] = p[(cp + j) * 128];
            #pragma unroll
            for (int j = 0; j < 8; j++) h = q[j].x * h + q[j].y;
            cp += 8;
        }
        if (cp + 4 <= c) {
            float2 q[4];
            #pragma unroll
            for (int j = 0; j < 4; j++) q[j] = p[(cp + j) * 128];
            #pragma unroll
            for (int j = 0; j < 4; j++) h = q[j].x * h + q[j].y;
            cp += 4;
        }
        for (; cp < c; cp++) {
            float2 q = p[cp * 128];
            h = q.x * h + q.y;
        }
    }

    const int e = tid >> 6, n = tid & 63;
    const float Aen = -__expf(A_log[e * 64 + n]);
    const float wb0 = W_x[1 + n],  wb1 = W_x[129 + 1 + n];
    const float wc0 = W_x[65 + n], wc1 = W_x[129 + 65 + n];
    const float wz0 = W_in[2], wz1 = W_in[3];
    const float D0 = D_skip[0], D1 = D_skip[1];
    const float wo0 = W_out[0], wo1 = W_out[1];
    __syncthreads();

    for (int tile = 0; tile < CL / T; tile++) {
        const int t0 = tile * T;
        if (e == 0) {
            #pragma unroll 8
            for (int t = 0; t < T; t++) {
                float4 v = s_ud[t0 + t];
                float Bn = v.x * wb0 + v.y * wb1;
                float Cn = v.x * wc0 + v.y * wc1;
                float dA = __expf(v.z * Aen);
                h = dA * h + (v.z * v.x) * Bn;
                ps[(t * 2 + 0) * PSTR + n] = h * Cn;
            }
        } else {
            #pragma unroll 8
            for (int t = 0; t < T; t++) {
                float4 v = s_ud[t0 + t];
                float Bn = v.x * wb0 + v.y * wb1;
                float Cn = v.x * wc0 + v.y * wc1;
                float dA = __expf(v.w * Aen);
                h = dA * h + (v.w * v.y) * Bn;
                ps[(t * 2 + 1) * PSTR + n] = h * Cn;
            }
        }
        __syncthreads();
        {   // half-row partial sums, float2 (8B-aligned since PSTR even)
            const int r = tid >> 1, half = tid & 1;
            const float2* row = (const float2*)&ps[r * PSTR + half * 32];
            float a0 = 0, a1 = 0;
            #pragma unroll
            for (int j = 0; j < 16; j += 2) {
                float2 p0 = row[j], p1 = row[j + 1];
                a0 += p0.x + p0.y;
                a1 += p1.x + p1.y;
            }
            pp[tid] = a0 + a1;
        }
        __syncthreads();
        if (tid < T) {
            const int t = tid, l = t0 + t;
            float4 v = s_ud[l];
            float y0 = pp[(t * 2 + 0) * 2 + 0] + pp[(t * 2 + 0) * 2 + 1] + v.x * D0;
            float y1 = pp[(t * 2 + 1) * 2 + 0] + pp[(t * 2 + 1) * 2 + 1] + v.y * D1;
            float xv = xs[l];
            float z0 = xv * wz0, z1 = xv * wz1;
            s_out[l] = y0 * (z0 * sigmoidf_(z0)) * wo0 +
                       y1 * (z1 * sigmoidf_(z1)) * wo1 + xv;
        }
        __syncthreads();
    }
    out[base + tid] = s_out[tid];
}

extern "C" void kernel_launch(void* const* d_in, const int* in_sizes, int n_in,
                              void* d_out, int out_size, void* d_ws, size_t ws_size,
                              hipStream_t stream) {
    const float* x      = (const float*)d_in[0];
    const float* W_in   = (const float*)d_in[1];   // [4,1,4]
    const float* conv_w = (const float*)d_in[2];   // [4,2,4]
    const float* conv_b = (const float*)d_in[3];   // [4,2]
    const float* W_x    = (const float*)d_in[4];   // [4,2,129]
    const float* W_dt   = (const float*)d_in[5];   // [4,1,2]
    const float* b_dt   = (const float*)d_in[6];   // [4,2]
    const float* A_log  = (const float*)d_in[7];   // [4,2,64]
    const float* D_skip = (const float*)d_in[8];   // [4,2]
    const float* W_out  = (const float*)d_in[9];   // [4,2,1]
    float* out = (float*)d_out;

    float* ws   = (float*)d_ws;
    float4* ud  = (float4*)ws;                           // B*L float4
    float2* PS  = (float2*)(ws + (size_t)Bsz * Lsz * 4); // B*NC*128 float2
    float* buf0 = ws + (size_t)Bsz * Lsz * 4 + (size_t)Bsz * NC * 128 * 2;
    float* buf1 = buf0 + (size_t)Bsz * Lsz;

    const float* cur = x;
    for (int i = 0; i < 4; i++) {
        float* o = (i == 3) ? out : ((i & 1) ? buf1 : buf0);
        k_scanA<<<dim3(NC, Bsz), 128, 0, stream>>>(
            cur, W_in + i * 4, conv_w + i * 8, conv_b + i * 2,
            W_x + i * 258, W_dt + i * 2, b_dt + i * 2, A_log + i * 128,
            ud, PS);
        k_scanB<<<dim3(NC, Bsz), 128, 0, stream>>>(
            cur, ud, PS, W_in + i * 4, W_x + i * 258,
            A_log + i * 128, D_skip + i * 2, W_out + i * 2, o);
        cur = o;
    }
}